// Round 11
// baseline (768.502 us; speedup 1.0000x reference)
//
#include <hip/hip_runtime.h>
#include <stdint.h>

#define NB 8
#define NP 4096
#define NS 1024
#define NK 64
#define ND 64
#define NH 64
#define NCO 128

#define FPS_T 512
#define PPT (NP / FPS_T)   // 8 points per thread

// padded K strides (in halves) for conflict-free b128 LDS access
#define K1P 104            // layer1 K: 64 x-ch + 3 xyz + zeros to 96, padded to 104
#define K2P 72             // layer2/3 K: 64, padded to 72

// workspace layout (bytes)
#define WS_WIDX 0          // int[NB*NS] per-step winner index tokens (32 KB)

typedef _Float16 half8v  __attribute__((ext_vector_type(8)));
typedef _Float16 half4v  __attribute__((ext_vector_type(4)));
typedef _Float16 half2v  __attribute__((ext_vector_type(2)));
typedef float    floatx4 __attribute__((ext_vector_type(4)));
typedef float    floatx2 __attribute__((ext_vector_type(2)));

// DPP move helper (ctrl must be compile-time constant)
template <int CTRL>
__device__ __forceinline__ float dpp_mov_f32(float x) {
    return __int_as_float(__builtin_amdgcn_update_dpp(
        0, __float_as_int(x), CTRL, 0xf, 0xf, true));
}

// ---------------- Fused kernel: fps producers + ballq/mlp consumers ----------
// Grid = 256 blocks x 512 threads; LDS 66 KB + launch_bounds(512,2) => all
// blocks co-resident, spin-wait deadlock-free.
// Blocks 0..7: fps with PACKED-f32 update loop (v_pk_mul/add_f32 — per-half
// IEEE RN, bit-identical to scalar; min stays scalar v_min_f32). Argmax =
// exact value max tree + first-index equality scan (identical tie semantics).
// Tokens latched in registers, flushed 16-wide per 16 steps (R10).
// Blocks 8..255: consumers stage W->f16-transposed in LDS themselves (wt
// pre-kernel deleted), hoist frags to registers, then spin on tokens and run
// the proven single-wave ballq + MFMA mlp; they also write new_xyz from
// pos[token] (bit-identical to producer's sp rows).
__global__ __launch_bounds__(512, 2) void fused_kernel(
        const float* __restrict__ x, const float* __restrict__ pos,
        const float* __restrict__ W1, const float* __restrict__ b1v,
        const float* __restrict__ W2, const float* __restrict__ b2v,
        const float* __restrict__ W3, const float* __restrict__ b3v,
        float* __restrict__ new_xyz, float* __restrict__ out, int* widx)
{
    __shared__ alignas(16) char smem[65664];
    const int tid  = threadIdx.x;
    const int lane = tid & 63;
    const int wv   = tid >> 6;

    if (blockIdx.x < NB) {
        // ================= FPS (packed-f32 update, R10 publish) ==============
#pragma clang fp contract(off)
        const int b = blockIdx.x;
        float4* sp = (float4*)smem;                               // 64 KB
        unsigned long long* kbuf = (unsigned long long*)(smem + 65536); // [2][8]

        const float* p = pos + (size_t)b * NP * 3;
        for (int i = tid; i < NP; i += FPS_T) {
            sp[i] = make_float4(p[i * 3 + 0], p[i * 3 + 1], p[i * 3 + 2], 0.0f);
        }
        __syncthreads();

        floatx2 px2[4], py2[4], pz2[4], md2[4];
#pragma unroll
        for (int pr = 0; pr < 4; ++pr) {
            float4 v0 = sp[tid * PPT + 2 * pr];
            float4 v1 = sp[tid * PPT + 2 * pr + 1];
            px2[pr][0] = v0.x; px2[pr][1] = v1.x;
            py2[pr][0] = v0.y; py2[pr][1] = v1.y;
            pz2[pr][0] = v0.z; pz2[pr][1] = v1.z;
            md2[pr][0] = 1e10f; md2[pr][1] = 1e10f;
        }

        int last = 0;
        if (tid == 0) {   // s=0 token
            __hip_atomic_store(widx + b * NS, 0, __ATOMIC_RELAXED,
                               __HIP_MEMORY_SCOPE_AGENT);
        }
        int tok = 0;      // per-lane latched token (wave 0 lanes 0..15 flush)

        int par = 0;
        for (int s = 1; s < NS; ++s) {
            const float4 lp = sp[last];
            const floatx2 lxv = {lp.x, lp.x};
            const floatx2 lyv = {lp.y, lp.y};
            const floatx2 lzv = {lp.z, lp.z};

            // packed update: v_pk_sub/mul/add (exact IEEE per half),
            // scalar v_min per element (same op as reference jnp.minimum)
            float m[8];
#pragma unroll
            for (int pr = 0; pr < 4; ++pr) {
                floatx2 dx = px2[pr] - lxv;
                floatx2 dy = py2[pr] - lyv;
                floatx2 dz = pz2[pr] - lzv;
                floatx2 d2 = dx * dx + dy * dy + dz * dz;  // contract(off)
                float m0 = (md2[pr][0] < d2[0]) ? md2[pr][0] : d2[0];
                float m1 = (md2[pr][1] < d2[1]) ? md2[pr][1] : d2[1];
                md2[pr][0] = m0; md2[pr][1] = m1;
                m[2 * pr] = m0; m[2 * pr + 1] = m1;
            }
            // exact value max + first-index equality scan (ties -> smallest j)
            float bv = fmaxf(fmaxf(fmaxf(m[0], m[1]), fmaxf(m[2], m[3])),
                             fmaxf(fmaxf(m[4], m[5]), fmaxf(m[6], m[7])));
            int jsel = 0;
#pragma unroll
            for (int j = 7; j >= 0; --j)
                jsel = (m[j] == bv) ? j : jsel;     // last write = smallest j
            int bi = tid * PPT + jsel;

            float r = bv;
            r = fmaxf(r, dpp_mov_f32<0x111>(r));   // row_shr:1
            r = fmaxf(r, dpp_mov_f32<0x112>(r));   // row_shr:2
            r = fmaxf(r, dpp_mov_f32<0x114>(r));   // row_shr:4
            r = fmaxf(r, dpp_mov_f32<0x118>(r));   // row_shr:8
            r = fmaxf(r, dpp_mov_f32<0x142>(r));   // row_bcast:15
            r = fmaxf(r, dpp_mov_f32<0x143>(r));   // row_bcast:31
            const float gmax = __int_as_float(
                __builtin_amdgcn_readlane(__float_as_int(r), 63));

            unsigned long long mk = __ballot(bv == gmax);
            int wl = (int)__builtin_ctzll(mk);
            int bw = __builtin_amdgcn_readlane(bi, wl);

            if (lane == 0) {
                kbuf[par * 8 + wv] =
                    ((unsigned long long)__float_as_uint(gmax) << 32) |
                    (unsigned long long)(~(unsigned)bw);
            }
            __syncthreads();

            const ulonglong2* wb = (const ulonglong2*)(kbuf + par * 8);
            ulonglong2 q0 = wb[0], q1 = wb[1], q2 = wb[2], q3 = wb[3];
            unsigned long long a0 = (q0.y > q0.x) ? q0.y : q0.x;
            unsigned long long a1 = (q1.y > q1.x) ? q1.y : q1.x;
            unsigned long long a2 = (q2.y > q2.x) ? q2.y : q2.x;
            unsigned long long a3 = (q3.y > q3.x) ? q3.y : q3.x;
            unsigned long long b0 = (a1 > a0) ? a1 : a0;
            unsigned long long b1 = (a3 > a2) ? a3 : a2;
            unsigned long long g  = (b1 > b0) ? b1 : b0;

            last = (int)(~(unsigned)g);

            // latch token in the matching lane (all threads know `last`)
            if ((s & 15) == lane) tok = last;
            // flush 16 tokens as one coalesced store per 16 steps
            if ((s & 15) == 15 && wv == 0 && lane < 16) {
                __hip_atomic_store(widx + b * NS + (s - 15) + lane, tok,
                                   __ATOMIC_RELAXED, __HIP_MEMORY_SCOPE_AGENT);
            }
            par ^= 1;
        }
        return;
    }

    // ================= Consumer: ballq + gather + MLP + pool =================
    const int ci = blockIdx.x - NB;   // 0..247
    const int b  = ci & 7;
    const int r0 = ci >> 3;           // 0..30

    // Phase 1: stage weights f16-transposed into LDS (wt layout), then hoist
    // frags to registers. This region is reused for G/H после a barrier.
    _Float16* sWt = (_Float16*)smem;  // 20480 halves = 40960 B

    {   // W1t[64][104]: k<64 -> W1[(3+k)*64+j]; k<67 -> W1[(k-64)*64+j]; else 0
        const int j = tid & 63;
        for (int k = tid >> 6; k < K1P; k += 8) {
            float v = 0.f;
            if (k < 64)      v = W1[(3 + k) * 64 + j];
            else if (k < 67) v = W1[(k - 64) * 64 + j];
            sWt[j * K1P + k] = (_Float16)v;
        }
        for (int k = tid >> 6; k < K2P; k += 8) {
            float v = (k < 64) ? W2[k * 64 + j] : 0.f;
            sWt[6656 + j * K2P + k] = (_Float16)v;
        }
        const int r = tid & 127;
        for (int k = tid >> 7; k < K2P; k += 4) {
            float v = (k < 64) ? W3[k * 128 + r] : 0.f;
            sWt[11264 + r * K2P + k] = (_Float16)v;
        }
    }
    __syncthreads();

    const int qd = lane >> 4;         // quad
    const int c  = lane & 15;         // col within MFMA tile
    const int myrow = wv * 16 + c;    // neighbor row (waves 0-3 only)

    half8v a1[3][4], a2[2][4], a3[2][8];
    if (tid < 256) {
#pragma unroll
        for (int ks = 0; ks < 3; ++ks)
#pragma unroll
            for (int mt = 0; mt < 4; ++mt)
                a1[ks][mt] = *(const half8v*)&sWt[(mt * 16 + c) * K1P + ks * 32 + qd * 8];
#pragma unroll
        for (int ks = 0; ks < 2; ++ks)
#pragma unroll
            for (int mt = 0; mt < 4; ++mt)
                a2[ks][mt] = *(const half8v*)&sWt[6656 + (mt * 16 + c) * K2P + ks * 32 + qd * 8];
#pragma unroll
        for (int ks = 0; ks < 2; ++ks)
#pragma unroll
            for (int mt = 0; mt < 8; ++mt)
                a3[ks][mt] = *(const half8v*)&sWt[11264 + (mt * 16 + c) * K2P + ks * 32 + qd * 8];
    }
    __syncthreads();   // frags read; smem now reusable

    _Float16* G   = (_Float16*)smem;            // 64*K1P halves = 13312 B
    _Float16* H1  = (_Float16*)(smem + 13312);  // 64*K2P = 9216 B
    _Float16* H2  = (_Float16*)(smem + 22528);  // 9216 B
    float*    CW  = (float*)(smem + 31744);     // 4*NCO = 2048 B
    float*    Lb  = (float*)(smem + 33792);     // 128 floats = 512 B
    short*  nbr_s = (short*)(smem + 34304);     // 128 B
    float*    qv  = (float*)(smem + 34432);     // 12 B

    float b3r = 0.f;
    if (tid < 256) {
        if (tid < 64) { Lb[tid] = b1v[tid]; Lb[64 + tid] = b2v[tid]; }
        if (tid < NCO) b3r = b3v[tid];
        half8v z = {};
        for (int i = tid; i < (64 * K1P) / 8; i += 256) ((half8v*)G)[i] = z;
    }

    for (int s = r0; s < NS; s += 31) {
        const int bs = b * NS + s;

        // ---- spin on the self-describing token (poison 0xAA.. < 0) ----
        int idx = -1, guard = 0;
        for (;;) {
            idx = __hip_atomic_load(widx + bs, __ATOMIC_RELAXED,
                                    __HIP_MEMORY_SCOPE_AGENT);
            if (idx >= 0) break;
            __builtin_amdgcn_s_sleep(8);
            if (++guard > (1 << 26)) break;   // escape hatch: fail loud, not hang
        }
        const int qidx = (idx >= 0 && idx < NP) ? idx : 0;

        // ---- wave 0: ball query into LDS; also writes new_xyz for this query --
        if (wv == 0) {
#pragma clang fp contract(off)
            const float* p = pos + (size_t)b * NP * 3;
            const float qx = p[qidx * 3 + 0];
            const float qy = p[qidx * 3 + 1];
            const float qz = p[qidx * 3 + 2];
            if (lane == 0) {
                qv[0] = qx; qv[1] = qy; qv[2] = qz;
                float* o = new_xyz + (size_t)bs * 3;
                o[0] = qx; o[1] = qy; o[2] = qz;
            }
            int cnt = 0;
            for (int n0 = 0; n0 < NP; n0 += 64) {
                const int n = n0 + lane;
                float dx = qx - p[n * 3 + 0];
                float dy = qy - p[n * 3 + 1];
                float dz = qz - p[n * 3 + 2];
                float d2 = dx * dx + dy * dy + dz * dz;   // contract(off)
                bool within = d2 < 0.04f;                 // r^2, strict <
                unsigned long long m = __ballot(within);
                if (within) {
                    int slot = cnt + __popcll(m & ((1ull << lane) - 1ull));
                    if (slot < NK) nbr_s[slot] = (short)n;
                }
                cnt += (int)__popcll(m);
                if (cnt >= NK) break;
            }
            if (cnt < NK) {
                if (lane < NK - cnt) nbr_s[cnt + lane] = (short)-1;
            }
        }
        __syncthreads();   // nbr_s, qv ready

        // ---- gather (waves 0-3): thread -> neighbor tid>>2, channel quarter ----
        if (tid < 256) {
            const int ni = tid >> 2;
            const int p4 = tid & 3;
            const int n  = (int)nbr_s[ni];
            const int nn = (n < 0) ? (NP - 1) : n;    // ref: points[-1] padding
            const float* xr = x + ((size_t)b * NP + nn) * ND + p4 * 16;
#pragma unroll
            for (int i = 0; i < 4; ++i) {
                float4 v = *(const float4*)(xr + 4 * i);
                half4v h;
                h[0] = (_Float16)v.x; h[1] = (_Float16)v.y;
                h[2] = (_Float16)v.z; h[3] = (_Float16)v.w;
                *(half4v*)&G[ni * K1P + p4 * 16 + 4 * i] = h;
            }
            if (p4 == 0) {
                const float* pr = pos + (size_t)(b * NP + nn) * 3;
                float gx = pr[0] - qv[0];
                float gy = pr[1] - qv[1];
                float gz = pr[2] - qv[2];
                half2v h2; h2[0] = (_Float16)gx; h2[1] = (_Float16)gy;
                *(half2v*)&G[ni * K1P + 64] = h2;
                G[ni * K1P + 66] = (_Float16)gz;
            }
        }
        __syncthreads();

        if (tid < 256) {
            // ---- layer 1: K=96 (3 steps), out 64 ch ----
            {
                floatx4 acc[4] = {};
#pragma unroll
                for (int ks = 0; ks < 3; ++ks) {
                    half8v bf = *(const half8v*)&G[myrow * K1P + ks * 32 + qd * 8];
#pragma unroll
                    for (int mt = 0; mt < 4; ++mt)
                        acc[mt] = __builtin_amdgcn_mfma_f32_16x16x32_f16(a1[ks][mt], bf, acc[mt], 0, 0, 0);
                }
#pragma unroll
                for (int mt = 0; mt < 4; ++mt) {
                    float4 bb = *(const float4*)&Lb[mt * 16 + qd * 4];
                    half4v h;
                    h[0] = (_Float16)fmaxf(acc[mt][0] + bb.x, 0.f);
                    h[1] = (_Float16)fmaxf(acc[mt][1] + bb.y, 0.f);
                    h[2] = (_Float16)fmaxf(acc[mt][2] + bb.z, 0.f);
                    h[3] = (_Float16)fmaxf(acc[mt][3] + bb.w, 0.f);
                    *(half4v*)&H1[myrow * K2P + mt * 16 + qd * 4] = h;
                }
            }
            // ---- layer 2: K=64 (2 steps), out 64 ch ----
            {
                floatx4 acc[4] = {};
#pragma unroll
                for (int ks = 0; ks < 2; ++ks) {
                    half8v bf = *(const half8v*)&H1[myrow * K2P + ks * 32 + qd * 8];
#pragma unroll
                    for (int mt = 0; mt < 4; ++mt)
                        acc[mt] = __builtin_amdgcn_mfma_f32_16x16x32_f16(a2[ks][mt], bf, acc[mt], 0, 0, 0);
                }
#pragma unroll
                for (int mt = 0; mt < 4; ++mt) {
                    float4 bb = *(const float4*)&Lb[64 + mt * 16 + qd * 4];
                    half4v h;
                    h[0] = (_Float16)fmaxf(acc[mt][0] + bb.x, 0.f);
                    h[1] = (_Float16)fmaxf(acc[mt][1] + bb.y, 0.f);
                    h[2] = (_Float16)fmaxf(acc[mt][2] + bb.z, 0.f);
                    h[3] = (_Float16)fmaxf(acc[mt][3] + bb.w, 0.f);
                    *(half4v*)&H2[myrow * K2P + mt * 16 + qd * 4] = h;
                }
            }
            // ---- layer 3 (swapped operands): C rows = neighbors ----
            {
                floatx4 acc3[8] = {};
#pragma unroll
                for (int ks = 0; ks < 2; ++ks) {
                    half8v av = *(const half8v*)&H2[myrow * K2P + ks * 32 + qd * 8];
#pragma unroll
                    for (int mt = 0; mt < 8; ++mt)
                        acc3[mt] = __builtin_amdgcn_mfma_f32_16x16x32_f16(av, a3[ks][mt], acc3[mt], 0, 0, 0);
                }
                const short* np4 = &nbr_s[wv * 16 + qd * 4];
                const bool v0 = np4[0] >= 0, v1 = np4[1] >= 0;
                const bool v2 = np4[2] >= 0, v3 = np4[3] >= 0;
#pragma unroll
                for (int mt = 0; mt < 8; ++mt) {
                    float m = v0 ? acc3[mt][0] : -INFINITY;
                    m = fmaxf(m, v1 ? acc3[mt][1] : -INFINITY);
                    m = fmaxf(m, v2 ? acc3[mt][2] : -INFINITY);
                    m = fmaxf(m, v3 ? acc3[mt][3] : -INFINITY);
                    m = fmaxf(m, __shfl_xor(m, 16));
                    m = fmaxf(m, __shfl_xor(m, 32));
                    if (qd == 0) CW[wv * NCO + mt * 16 + c] = m;
                }
            }
        }
        __syncthreads();

        if (tid < NCO) {
            float m = fmaxf(fmaxf(CW[tid], CW[NCO + tid]),
                            fmaxf(CW[2 * NCO + tid], CW[3 * NCO + tid]));
            m += b3r;                                  // exact: add after max
            if (nbr_s[NK - 1] < 0) m = fmaxf(m, 0.f);  // ref's masked zeros
            out[(size_t)bs * NCO + tid] = m;
        }
        __syncthreads();   // protect nbr_s/G/CW before next query's ballq/gather
    }
}

extern "C" void kernel_launch(void* const* d_in, const int* in_sizes, int n_in,
                              void* d_out, int out_size, void* d_ws, size_t ws_size,
                              hipStream_t stream) {
    const float* x   = (const float*)d_in[0];
    const float* pos = (const float*)d_in[1];
    const float* W1  = (const float*)d_in[2];
    const float* b1  = (const float*)d_in[3];
    const float* W2  = (const float*)d_in[4];
    const float* b2  = (const float*)d_in[5];
    const float* W3  = (const float*)d_in[6];
    const float* b3  = (const float*)d_in[7];

    float* out0 = (float*)d_out;                        // [B,S,128]
    float* nxyz = out0 + (size_t)NB * NS * NCO;         // [B,S,3]
    int*   widxp = (int*)((char*)d_ws + WS_WIDX);       // tokens (0xAA poison < 0)

    fused_kernel<<<256, 512, 0, stream>>>(x, pos, W1, b1, W2, b2, W3, b3,
                                          nxyz, out0, widxp);
}

// Round 12
// 754.092 us; speedup vs baseline: 1.0191x; 1.0191x over previous
//
#include <hip/hip_runtime.h>
#include <stdint.h>

#define NB 8
#define NP 4096
#define NS 1024
#define NK 64
#define ND 64
#define NH 64
#define NCO 128

#define FPS_T 512
#define PPT (NP / FPS_T)   // 8 points per thread

// padded K strides (in halves) for conflict-free b128 LDS access
#define K1P 104            // layer1 K: 64 x-ch + 3 xyz + zeros to 96, padded to 104
#define K2P 72             // layer2/3 K: 64, padded to 72

// workspace layout (bytes)
#define WS_WIDX 0          // int[NB*NS] per-step winner index tokens (32 KB)
#define WS_WT   32768      // _Float16 weights (20480 halves = 40 KB)

typedef _Float16 half8v __attribute__((ext_vector_type(8)));
typedef _Float16 half4v __attribute__((ext_vector_type(4)));
typedef _Float16 half2v __attribute__((ext_vector_type(2)));
typedef float    floatx4 __attribute__((ext_vector_type(4)));

// DPP move helper (ctrl must be compile-time constant)
template <int CTRL>
__device__ __forceinline__ float dpp_mov_f32(float x) {
    return __int_as_float(__builtin_amdgcn_update_dpp(
        0, __float_as_int(x), CTRL, 0xf, 0xf, true));
}

// ---------------- Kernel 0: weight transpose + f16 convert ----------------
__global__ __launch_bounds__(64) void wt_kernel(const float* __restrict__ W1,
                                                const float* __restrict__ W2,
                                                const float* __restrict__ W3,
                                                _Float16* __restrict__ wt)
{
    const int j = blockIdx.x;
    const int t = threadIdx.x;
    if (j < 64) {
        for (int k = t; k < K1P; k += 64) {
            float v = 0.f;
            if (k < 64)       v = W1[(3 + k) * 64 + j];
            else if (k < 67)  v = W1[(k - 64) * 64 + j];
            wt[j * K1P + k] = (_Float16)v;
        }
    } else if (j < 128) {
        const int r = j - 64;
        for (int k = t; k < K2P; k += 64) {
            float v = (k < 64) ? W2[k * 64 + r] : 0.f;
            wt[6656 + r * K2P + k] = (_Float16)v;
        }
    } else {
        const int r = j - 128;
        for (int k = t; k < K2P; k += 64) {
            float v = (k < 64) ? W3[k * 128 + r] : 0.f;
            wt[11264 + r * K2P + k] = (_Float16)v;
        }
    }
}

// ---------------- Fused kernel: fps producers + ballq/mlp consumers ----------
// Grid = 256 blocks x 512 threads; LDS 66 KB + launch_bounds(512,2) => all
// blocks co-resident, spin-wait deadlock-free.
// Blocks 0..7: R6-exact fps. Producer issues NO per-step global stores:
// tokens latched in registers (lane L of wave 0 holds winner of step with
// s&15==L) and flushed as ONE coalesced 16-dword store per 16 steps.
// new_xyz written by CONSUMERS from pos[token] (bit-identical).
// Blocks 8..255: consumer ci handles batch ci&7, queries s ≡ ci>>3 (mod 31);
// spins on the self-describing token (0xAA poison < 0), then proven
// single-wave ballq + R6 MFMA mlp.
__global__ __launch_bounds__(512, 2) void fused_kernel(
        const float* __restrict__ x, const float* __restrict__ pos,
        const float* __restrict__ b1v, const float* __restrict__ b2v,
        const float* __restrict__ b3v,
        const _Float16* __restrict__ wt,
        float* __restrict__ new_xyz, float* __restrict__ out, int* widx)
{
    __shared__ alignas(16) char smem[65664];
    const int tid  = threadIdx.x;
    const int lane = tid & 63;
    const int wv   = tid >> 6;

    if (blockIdx.x < NB) {
        // ================= FPS (R6-proven structure, batched publish) ========
#pragma clang fp contract(off)
        const int b = blockIdx.x;
        float4* sp = (float4*)smem;                               // 64 KB
        unsigned long long* kbuf = (unsigned long long*)(smem + 65536); // [2][8]

        const float* p = pos + (size_t)b * NP * 3;
        for (int i = tid; i < NP; i += FPS_T) {
            sp[i] = make_float4(p[i * 3 + 0], p[i * 3 + 1], p[i * 3 + 2], 0.0f);
        }
        __syncthreads();

        float px[PPT], py[PPT], pz[PPT], md[PPT];
#pragma unroll
        for (int j = 0; j < PPT; ++j) {
            float4 v = sp[tid * PPT + j];
            px[j] = v.x; py[j] = v.y; pz[j] = v.z;
            md[j] = 1e10f;
        }

        int last = 0;
        if (tid == 0) {   // s=0 token (drains once at first barrier)
            __hip_atomic_store(widx + b * NS, 0, __ATOMIC_RELAXED,
                               __HIP_MEMORY_SCOPE_AGENT);
        }
        int tok = 0;      // per-lane latched token (wave 0 lanes 0..15 flush)

        int par = 0;
        for (int s = 1; s < NS; ++s) {
            const float4 lp = sp[last];
            const float lx = lp.x, ly = lp.y, lz = lp.z;

            float bv = 0.0f;
            int   bi = tid * PPT;
#pragma unroll
            for (int j = 0; j < PPT; ++j) {
                float dx = px[j] - lx;
                float dy = py[j] - ly;
                float dz = pz[j] - lz;
                float d2 = dx * dx + dy * dy + dz * dz;  // contract(off): exact
                float m  = (md[j] < d2) ? md[j] : d2;    // jnp.minimum
                md[j] = m;
                if (m > bv) { bv = m; bi = tid * PPT + j; }
            }

            float r = bv;
            r = fmaxf(r, dpp_mov_f32<0x111>(r));   // row_shr:1
            r = fmaxf(r, dpp_mov_f32<0x112>(r));   // row_shr:2
            r = fmaxf(r, dpp_mov_f32<0x114>(r));   // row_shr:4
            r = fmaxf(r, dpp_mov_f32<0x118>(r));   // row_shr:8
            r = fmaxf(r, dpp_mov_f32<0x142>(r));   // row_bcast:15
            r = fmaxf(r, dpp_mov_f32<0x143>(r));   // row_bcast:31
            const float gmax = __int_as_float(
                __builtin_amdgcn_readlane(__float_as_int(r), 63));

            unsigned long long mk = __ballot(bv == gmax);
            int wl = (int)__builtin_ctzll(mk);
            int bw = __builtin_amdgcn_readlane(bi, wl);

            if (lane == 0) {
                kbuf[par * 8 + wv] =
                    ((unsigned long long)__float_as_uint(gmax) << 32) |
                    (unsigned long long)(~(unsigned)bw);
            }
            __syncthreads();

            const ulonglong2* wb = (const ulonglong2*)(kbuf + par * 8);
            ulonglong2 q0 = wb[0], q1 = wb[1], q2 = wb[2], q3 = wb[3];
            unsigned long long a0 = (q0.y > q0.x) ? q0.y : q0.x;
            unsigned long long a1 = (q1.y > q1.x) ? q1.y : q1.x;
            unsigned long long a2 = (q2.y > q2.x) ? q2.y : q2.x;
            unsigned long long a3 = (q3.y > q3.x) ? q3.y : q3.x;
            unsigned long long b0 = (a1 > a0) ? a1 : a0;
            unsigned long long b1 = (a3 > a2) ? a3 : a2;
            unsigned long long g  = (b1 > b0) ? b1 : b0;

            last = (int)(~(unsigned)g);

            // latch token in the matching lane (all threads know `last`)
            if ((s & 15) == lane) tok = last;
            // flush 16 tokens as one coalesced store per 16 steps
            if ((s & 15) == 15 && wv == 0 && lane < 16) {
                __hip_atomic_store(widx + b * NS + (s - 15) + lane, tok,
                                   __ATOMIC_RELAXED, __HIP_MEMORY_SCOPE_AGENT);
            }
            par ^= 1;
        }
        return;
    }

    // ================= Consumer: ballq + gather + MLP + pool =================
    const int ci = blockIdx.x - NB;   // 0..247
    const int b  = ci & 7;
    const int r0 = ci >> 3;           // 0..30

    _Float16* G   = (_Float16*)smem;            // 64*K1P halves = 13312 B
    _Float16* H1  = (_Float16*)(smem + 13312);  // 64*K2P = 9216 B
    _Float16* H2  = (_Float16*)(smem + 22528);  // 9216 B
    float*    CW  = (float*)(smem + 31744);     // 4*NCO = 2048 B
    float*    Lb  = (float*)(smem + 33792);     // 128 floats = 512 B
    short*  nbr_s = (short*)(smem + 34304);     // 128 B
    float*    qv  = (float*)(smem + 34432);     // 12 B

    const int qd = lane >> 4;         // quad
    const int c  = lane & 15;         // col within MFMA tile
    const int myrow = wv * 16 + c;    // neighbor row (waves 0-3 only)

    // weight frag hoist + bias staging (waves 0-3)
    half8v a1[3][4], a2[2][4], a3[2][8];
    float b3r = 0.f;
    if (tid < 256) {
#pragma unroll
        for (int ks = 0; ks < 3; ++ks)
#pragma unroll
            for (int mt = 0; mt < 4; ++mt)
                a1[ks][mt] = *(const half8v*)&wt[(mt * 16 + c) * K1P + ks * 32 + qd * 8];
#pragma unroll
        for (int ks = 0; ks < 2; ++ks)
#pragma unroll
            for (int mt = 0; mt < 4; ++mt)
                a2[ks][mt] = *(const half8v*)&wt[6656 + (mt * 16 + c) * K2P + ks * 32 + qd * 8];
#pragma unroll
        for (int ks = 0; ks < 2; ++ks)
#pragma unroll
            for (int mt = 0; mt < 8; ++mt)
                a3[ks][mt] = *(const half8v*)&wt[11264 + (mt * 16 + c) * K2P + ks * 32 + qd * 8];
        if (tid < 64) { Lb[tid] = b1v[tid]; Lb[64 + tid] = b2v[tid]; }
        if (tid < NCO) b3r = b3v[tid];
        half8v z = {};
        for (int i = tid; i < (64 * K1P) / 8; i += 256) ((half8v*)G)[i] = z;
    }

    for (int s = r0; s < NS; s += 31) {
        const int bs = b * NS + s;

        // ---- spin on the self-describing token (poison 0xAA.. < 0) ----
        int idx = -1, guard = 0;
        for (;;) {
            idx = __hip_atomic_load(widx + bs, __ATOMIC_RELAXED,
                                    __HIP_MEMORY_SCOPE_AGENT);
            if (idx >= 0) break;
            __builtin_amdgcn_s_sleep(8);
            if (++guard > (1 << 26)) break;   // escape hatch: fail loud, not hang
        }
        const int qidx = (idx >= 0 && idx < NP) ? idx : 0;

        // ---- wave 0: ball query into LDS (query coords from pos[qidx]);
        //      also writes this query's new_xyz (bit-identical to producer's) --
        if (wv == 0) {
#pragma clang fp contract(off)
            const float* p = pos + (size_t)b * NP * 3;
            const float qx = p[qidx * 3 + 0];
            const float qy = p[qidx * 3 + 1];
            const float qz = p[qidx * 3 + 2];
            if (lane == 0) {
                qv[0] = qx; qv[1] = qy; qv[2] = qz;
                float* o = new_xyz + (size_t)bs * 3;
                o[0] = qx; o[1] = qy; o[2] = qz;
            }
            int cnt = 0;
            for (int n0 = 0; n0 < NP; n0 += 64) {
                const int n = n0 + lane;
                float dx = qx - p[n * 3 + 0];
                float dy = qy - p[n * 3 + 1];
                float dz = qz - p[n * 3 + 2];
                float d2 = dx * dx + dy * dy + dz * dz;   // contract(off)
                bool within = d2 < 0.04f;                 // r^2, strict <
                unsigned long long m = __ballot(within);
                if (within) {
                    int slot = cnt + __popcll(m & ((1ull << lane) - 1ull));
                    if (slot < NK) nbr_s[slot] = (short)n;
                }
                cnt += (int)__popcll(m);
                if (cnt >= NK) break;
            }
            if (cnt < NK) {
                if (lane < NK - cnt) nbr_s[cnt + lane] = (short)-1;
            }
        }
        __syncthreads();   // nbr_s, qv ready

        // ---- gather (waves 0-3): thread -> neighbor tid>>2, channel quarter ----
        if (tid < 256) {
            const int ni = tid >> 2;
            const int p4 = tid & 3;
            const int n  = (int)nbr_s[ni];
            const int nn = (n < 0) ? (NP - 1) : n;    // ref: points[-1] padding
            const float* xr = x + ((size_t)b * NP + nn) * ND + p4 * 16;
#pragma unroll
            for (int i = 0; i < 4; ++i) {
                float4 v = *(const float4*)(xr + 4 * i);
                half4v h;
                h[0] = (_Float16)v.x; h[1] = (_Float16)v.y;
                h[2] = (_Float16)v.z; h[3] = (_Float16)v.w;
                *(half4v*)&G[ni * K1P + p4 * 16 + 4 * i] = h;
            }
            if (p4 == 0) {
                const float* pr = pos + (size_t)(b * NP + nn) * 3;
                float gx = pr[0] - qv[0];
                float gy = pr[1] - qv[1];
                float gz = pr[2] - qv[2];
                half2v h2; h2[0] = (_Float16)gx; h2[1] = (_Float16)gy;
                *(half2v*)&G[ni * K1P + 64] = h2;
                G[ni * K1P + 66] = (_Float16)gz;
            }
        }
        __syncthreads();

        if (tid < 256) {
            // ---- layer 1: K=96 (3 steps), out 64 ch ----
            {
                floatx4 acc[4] = {};
#pragma unroll
                for (int ks = 0; ks < 3; ++ks) {
                    half8v bf = *(const half8v*)&G[myrow * K1P + ks * 32 + qd * 8];
#pragma unroll
                    for (int mt = 0; mt < 4; ++mt)
                        acc[mt] = __builtin_amdgcn_mfma_f32_16x16x32_f16(a1[ks][mt], bf, acc[mt], 0, 0, 0);
                }
#pragma unroll
                for (int mt = 0; mt < 4; ++mt) {
                    float4 bb = *(const float4*)&Lb[mt * 16 + qd * 4];
                    half4v h;
                    h[0] = (_Float16)fmaxf(acc[mt][0] + bb.x, 0.f);
                    h[1] = (_Float16)fmaxf(acc[mt][1] + bb.y, 0.f);
                    h[2] = (_Float16)fmaxf(acc[mt][2] + bb.z, 0.f);
                    h[3] = (_Float16)fmaxf(acc[mt][3] + bb.w, 0.f);
                    *(half4v*)&H1[myrow * K2P + mt * 16 + qd * 4] = h;
                }
            }
            // ---- layer 2: K=64 (2 steps), out 64 ch ----
            {
                floatx4 acc[4] = {};
#pragma unroll
                for (int ks = 0; ks < 2; ++ks) {
                    half8v bf = *(const half8v*)&H1[myrow * K2P + ks * 32 + qd * 8];
#pragma unroll
                    for (int mt = 0; mt < 4; ++mt)
                        acc[mt] = __builtin_amdgcn_mfma_f32_16x16x32_f16(a2[ks][mt], bf, acc[mt], 0, 0, 0);
                }
#pragma unroll
                for (int mt = 0; mt < 4; ++mt) {
                    float4 bb = *(const float4*)&Lb[64 + mt * 16 + qd * 4];
                    half4v h;
                    h[0] = (_Float16)fmaxf(acc[mt][0] + bb.x, 0.f);
                    h[1] = (_Float16)fmaxf(acc[mt][1] + bb.y, 0.f);
                    h[2] = (_Float16)fmaxf(acc[mt][2] + bb.z, 0.f);
                    h[3] = (_Float16)fmaxf(acc[mt][3] + bb.w, 0.f);
                    *(half4v*)&H2[myrow * K2P + mt * 16 + qd * 4] = h;
                }
            }
            // ---- layer 3 (swapped operands): C rows = neighbors ----
            {
                floatx4 acc3[8] = {};
#pragma unroll
                for (int ks = 0; ks < 2; ++ks) {
                    half8v av = *(const half8v*)&H2[myrow * K2P + ks * 32 + qd * 8];
#pragma unroll
                    for (int mt = 0; mt < 8; ++mt)
                        acc3[mt] = __builtin_amdgcn_mfma_f32_16x16x32_f16(av, a3[ks][mt], acc3[mt], 0, 0, 0);
                }
                const short* np4 = &nbr_s[wv * 16 + qd * 4];
                const bool v0 = np4[0] >= 0, v1 = np4[1] >= 0;
                const bool v2 = np4[2] >= 0, v3 = np4[3] >= 0;
#pragma unroll
                for (int mt = 0; mt < 8; ++mt) {
                    float m = v0 ? acc3[mt][0] : -INFINITY;
                    m = fmaxf(m, v1 ? acc3[mt][1] : -INFINITY);
                    m = fmaxf(m, v2 ? acc3[mt][2] : -INFINITY);
                    m = fmaxf(m, v3 ? acc3[mt][3] : -INFINITY);
                    m = fmaxf(m, __shfl_xor(m, 16));
                    m = fmaxf(m, __shfl_xor(m, 32));
                    if (qd == 0) CW[wv * NCO + mt * 16 + c] = m;
                }
            }
        }
        __syncthreads();

        if (tid < NCO) {
            float m = fmaxf(fmaxf(CW[tid], CW[NCO + tid]),
                            fmaxf(CW[2 * NCO + tid], CW[3 * NCO + tid]));
            m += b3r;                                  // exact: add after max
            if (nbr_s[NK - 1] < 0) m = fmaxf(m, 0.f);  // ref's masked zeros
            out[(size_t)bs * NCO + tid] = m;
        }
        __syncthreads();   // protect nbr_s/G/CW before next query's ballq/gather
    }
}

extern "C" void kernel_launch(void* const* d_in, const int* in_sizes, int n_in,
                              void* d_out, int out_size, void* d_ws, size_t ws_size,
                              hipStream_t stream) {
    const float* x   = (const float*)d_in[0];
    const float* pos = (const float*)d_in[1];
    const float* W1  = (const float*)d_in[2];
    const float* b1  = (const float*)d_in[3];
    const float* W2  = (const float*)d_in[4];
    const float* b2  = (const float*)d_in[5];
    const float* W3  = (const float*)d_in[6];
    const float* b3  = (const float*)d_in[7];

    float* out0 = (float*)d_out;                        // [B,S,128]
    float* nxyz = out0 + (size_t)NB * NS * NCO;         // [B,S,3]
    int*      widxp = (int*)((char*)d_ws + WS_WIDX);    // tokens (0xAA poison < 0)
    _Float16* wtp   = (_Float16*)((char*)d_ws + WS_WT); // f16 weights, 40 KB

    wt_kernel<<<256, 64, 0, stream>>>(W1, W2, W3, wtp);
    fused_kernel<<<256, 512, 0, stream>>>(x, pos, b1, b2, b3, wtp,
                                          nxyz, out0, widxp);
}

// Round 13
// 745.910 us; speedup vs baseline: 1.0303x; 1.0110x over previous
//
#include <hip/hip_runtime.h>
#include <stdint.h>

#define NB 8
#define NP 4096
#define NS 1024
#define NK 64
#define ND 64
#define NH 64
#define NCO 128

#define PPT2 16            // producer: 4 waves x 256 threads x 16 points

// padded K strides (in halves) for conflict-free b128 LDS access
#define K1P 104            // layer1 K: 64 x-ch + 3 xyz + zeros to 96, padded to 104
#define K2P 72             // layer2/3 K: 64, padded to 72

// workspace layout (bytes)
#define WS_WIDX 0          // int[NB*NS] per-step winner index tokens (32 KB)
#define WS_WT   32768      // _Float16 weights (20480 halves = 40 KB)

typedef _Float16 half8v __attribute__((ext_vector_type(8)));
typedef _Float16 half4v __attribute__((ext_vector_type(4)));
typedef _Float16 half2v __attribute__((ext_vector_type(2)));
typedef float    floatx4 __attribute__((ext_vector_type(4)));

// DPP move helper (ctrl must be compile-time constant)
template <int CTRL>
__device__ __forceinline__ float dpp_mov_f32(float x) {
    return __int_as_float(__builtin_amdgcn_update_dpp(
        0, __float_as_int(x), CTRL, 0xf, 0xf, true));
}

// ---------------- Kernel 0: weight transpose + f16 convert ----------------
__global__ __launch_bounds__(64) void wt_kernel(const float* __restrict__ W1,
                                                const float* __restrict__ W2,
                                                const float* __restrict__ W3,
                                                _Float16* __restrict__ wt)
{
    const int j = blockIdx.x;
    const int t = threadIdx.x;
    if (j < 64) {
        for (int k = t; k < K1P; k += 64) {
            float v = 0.f;
            if (k < 64)       v = W1[(3 + k) * 64 + j];
            else if (k < 67)  v = W1[(k - 64) * 64 + j];
            wt[j * K1P + k] = (_Float16)v;
        }
    } else if (j < 128) {
        const int r = j - 64;
        for (int k = t; k < K2P; k += 64) {
            float v = (k < 64) ? W2[k * 64 + r] : 0.f;
            wt[6656 + r * K2P + k] = (_Float16)v;
        }
    } else {
        const int r = j - 128;
        for (int k = t; k < K2P; k += 64) {
            float v = (k < 64) ? W3[k * 128 + r] : 0.f;
            wt[11264 + r * K2P + k] = (_Float16)v;
        }
    }
}

// ---------------- Fused kernel: fps producers + ballq/mlp consumers ----------
// Grid = 256 blocks x 512 threads; all blocks co-resident (1/CU) => spin-wait
// deadlock-free. Blocks 0..7: fps with FOUR update waves (256 thr x 16 pts,
// bit-exact R6 arithmetic) — waves 4..7 only match the one barrier per step
// (instant arrival: halves the real barrier population and the key tree is
// 4-wide). Tokens latched in registers, flushed 16-wide per 16 steps (R10).
// Blocks 8..255: consumers — token spin, single-wave ballq, MFMA mlp; they
// also write new_xyz from pos[token] (bit-identical to producer's sp rows).
__global__ __launch_bounds__(512, 2) void fused_kernel(
        const float* __restrict__ x, const float* __restrict__ pos,
        const float* __restrict__ b1v, const float* __restrict__ b2v,
        const float* __restrict__ b3v,
        const _Float16* __restrict__ wt,
        float* __restrict__ new_xyz, float* __restrict__ out, int* widx)
{
    __shared__ alignas(16) char smem[65664];
    const int tid  = threadIdx.x;
    const int lane = tid & 63;
    const int wv   = tid >> 6;

    if (blockIdx.x < NB) {
        // ================= FPS (4 update waves, R10 publish) =================
#pragma clang fp contract(off)
        const int b = blockIdx.x;
        float4* sp = (float4*)smem;                               // 64 KB
        unsigned long long* kbuf = (unsigned long long*)(smem + 65536); // [2][8]

        const float* p = pos + (size_t)b * NP * 3;
        for (int i = tid; i < NP; i += 512) {
            sp[i] = make_float4(p[i * 3 + 0], p[i * 3 + 1], p[i * 3 + 2], 0.0f);
        }
        __syncthreads();

        if (wv >= 4) {
            // barrier companions: one arrival per step, nothing else
            for (int s = 1; s < NS; ++s) __syncthreads();
            return;
        }

        float px[PPT2], py[PPT2], pz[PPT2], md[PPT2];
#pragma unroll
        for (int j = 0; j < PPT2; ++j) {
            float4 v = sp[tid * PPT2 + j];
            px[j] = v.x; py[j] = v.y; pz[j] = v.z;
            md[j] = 1e10f;
        }

        int last = 0;
        if (tid == 0) {   // s=0 token
            __hip_atomic_store(widx + b * NS, 0, __ATOMIC_RELAXED,
                               __HIP_MEMORY_SCOPE_AGENT);
        }
        int tok = 0;      // per-lane latched token (wave 0 lanes 0..15 flush)

        int par = 0;
        for (int s = 1; s < NS; ++s) {
            const float4 lp = sp[last];
            const float lx = lp.x, ly = lp.y, lz = lp.z;

            float bv = 0.0f;
            int   bi = tid * PPT2;
#pragma unroll
            for (int j = 0; j < PPT2; ++j) {
                float dx = px[j] - lx;
                float dy = py[j] - ly;
                float dz = pz[j] - lz;
                float d2 = dx * dx + dy * dy + dz * dz;  // contract(off): exact
                float m  = (md[j] < d2) ? md[j] : d2;    // jnp.minimum
                md[j] = m;
                if (m > bv) { bv = m; bi = tid * PPT2 + j; }
            }

            float r = bv;
            r = fmaxf(r, dpp_mov_f32<0x111>(r));   // row_shr:1
            r = fmaxf(r, dpp_mov_f32<0x112>(r));   // row_shr:2
            r = fmaxf(r, dpp_mov_f32<0x114>(r));   // row_shr:4
            r = fmaxf(r, dpp_mov_f32<0x118>(r));   // row_shr:8
            r = fmaxf(r, dpp_mov_f32<0x142>(r));   // row_bcast:15
            r = fmaxf(r, dpp_mov_f32<0x143>(r));   // row_bcast:31
            const float gmax = __int_as_float(
                __builtin_amdgcn_readlane(__float_as_int(r), 63));

            unsigned long long mk = __ballot(bv == gmax);
            int wl = (int)__builtin_ctzll(mk);
            int bw = __builtin_amdgcn_readlane(bi, wl);

            if (lane == 0) {
                kbuf[par * 8 + wv] =
                    ((unsigned long long)__float_as_uint(gmax) << 32) |
                    (unsigned long long)(~(unsigned)bw);
            }
            __syncthreads();

            // 4-key tree (2 b128 reads, 3 compares)
            const ulonglong2* wb = (const ulonglong2*)(kbuf + par * 8);
            ulonglong2 q0 = wb[0], q1 = wb[1];
            unsigned long long a0 = (q0.y > q0.x) ? q0.y : q0.x;
            unsigned long long a1 = (q1.y > q1.x) ? q1.y : q1.x;
            unsigned long long g  = (a1 > a0) ? a1 : a0;

            last = (int)(~(unsigned)g);

            // latch token in the matching lane (all threads know `last`)
            if ((s & 15) == lane) tok = last;
            // flush 16 tokens as one coalesced store per 16 steps
            if ((s & 15) == 15 && wv == 0 && lane < 16) {
                __hip_atomic_store(widx + b * NS + (s - 15) + lane, tok,
                                   __ATOMIC_RELAXED, __HIP_MEMORY_SCOPE_AGENT);
            }
            par ^= 1;
        }
        return;
    }

    // ================= Consumer: ballq + gather + MLP + pool =================
    const int ci = blockIdx.x - NB;   // 0..247
    const int b  = ci & 7;
    const int r0 = ci >> 3;           // 0..30

    _Float16* G   = (_Float16*)smem;            // 64*K1P halves = 13312 B
    _Float16* H1  = (_Float16*)(smem + 13312);  // 64*K2P = 9216 B
    _Float16* H2  = (_Float16*)(smem + 22528);  // 9216 B
    float*    CW  = (float*)(smem + 31744);     // 4*NCO = 2048 B
    float*    Lb  = (float*)(smem + 33792);     // 128 floats = 512 B
    short*  nbr_s = (short*)(smem + 34304);     // 128 B
    float*    qv  = (float*)(smem + 34432);     // 12 B

    const int qd = lane >> 4;         // quad
    const int c  = lane & 15;         // col within MFMA tile
    const int myrow = wv * 16 + c;    // neighbor row (waves 0-3 only)

    // weight frag hoist + bias staging (waves 0-3)
    half8v a1[3][4], a2[2][4], a3[2][8];
    float b3r = 0.f;
    if (tid < 256) {
#pragma unroll
        for (int ks = 0; ks < 3; ++ks)
#pragma unroll
            for (int mt = 0; mt < 4; ++mt)
                a1[ks][mt] = *(const half8v*)&wt[(mt * 16 + c) * K1P + ks * 32 + qd * 8];
#pragma unroll
        for (int ks = 0; ks < 2; ++ks)
#pragma unroll
            for (int mt = 0; mt < 4; ++mt)
                a2[ks][mt] = *(const half8v*)&wt[6656 + (mt * 16 + c) * K2P + ks * 32 + qd * 8];
#pragma unroll
        for (int ks = 0; ks < 2; ++ks)
#pragma unroll
            for (int mt = 0; mt < 8; ++mt)
                a3[ks][mt] = *(const half8v*)&wt[11264 + (mt * 16 + c) * K2P + ks * 32 + qd * 8];
        if (tid < 64) { Lb[tid] = b1v[tid]; Lb[64 + tid] = b2v[tid]; }
        if (tid < NCO) b3r = b3v[tid];
        half8v z = {};
        for (int i = tid; i < (64 * K1P) / 8; i += 256) ((half8v*)G)[i] = z;
    }

    for (int s = r0; s < NS; s += 31) {
        const int bs = b * NS + s;

        // ---- spin on the self-describing token (poison 0xAA.. < 0) ----
        int idx = -1, guard = 0;
        for (;;) {
            idx = __hip_atomic_load(widx + bs, __ATOMIC_RELAXED,
                                    __HIP_MEMORY_SCOPE_AGENT);
            if (idx >= 0) break;
            __builtin_amdgcn_s_sleep(8);
            if (++guard > (1 << 26)) break;   // escape hatch: fail loud, not hang
        }
        const int qidx = (idx >= 0 && idx < NP) ? idx : 0;

        // ---- wave 0: ball query into LDS (query coords from pos[qidx]);
        //      also writes this query's new_xyz (bit-identical to producer's) --
        if (wv == 0) {
#pragma clang fp contract(off)
            const float* p = pos + (size_t)b * NP * 3;
            const float qx = p[qidx * 3 + 0];
            const float qy = p[qidx * 3 + 1];
            const float qz = p[qidx * 3 + 2];
            if (lane == 0) {
                qv[0] = qx; qv[1] = qy; qv[2] = qz;
                float* o = new_xyz + (size_t)bs * 3;
                o[0] = qx; o[1] = qy; o[2] = qz;
            }
            int cnt = 0;
            for (int n0 = 0; n0 < NP; n0 += 64) {
                const int n = n0 + lane;
                float dx = qx - p[n * 3 + 0];
                float dy = qy - p[n * 3 + 1];
                float dz = qz - p[n * 3 + 2];
                float d2 = dx * dx + dy * dy + dz * dz;   // contract(off)
                bool within = d2 < 0.04f;                 // r^2, strict <
                unsigned long long m = __ballot(within);
                if (within) {
                    int slot = cnt + __popcll(m & ((1ull << lane) - 1ull));
                    if (slot < NK) nbr_s[slot] = (short)n;
                }
                cnt += (int)__popcll(m);
                if (cnt >= NK) break;
            }
            if (cnt < NK) {
                if (lane < NK - cnt) nbr_s[cnt + lane] = (short)-1;
            }
        }
        __syncthreads();   // nbr_s, qv ready

        // ---- gather (waves 0-3): thread -> neighbor tid>>2, channel quarter ----
        if (tid < 256) {
            const int ni = tid >> 2;
            const int p4 = tid & 3;
            const int n  = (int)nbr_s[ni];
            const int nn = (n < 0) ? (NP - 1) : n;    // ref: points[-1] padding
            const float* xr = x + ((size_t)b * NP + nn) * ND + p4 * 16;
#pragma unroll
            for (int i = 0; i < 4; ++i) {
                float4 v = *(const float4*)(xr + 4 * i);
                half4v h;
                h[0] = (_Float16)v.x; h[1] = (_Float16)v.y;
                h[2] = (_Float16)v.z; h[3] = (_Float16)v.w;
                *(half4v*)&G[ni * K1P + p4 * 16 + 4 * i] = h;
            }
            if (p4 == 0) {
                const float* pr = pos + (size_t)(b * NP + nn) * 3;
                float gx = pr[0] - qv[0];
                float gy = pr[1] - qv[1];
                float gz = pr[2] - qv[2];
                half2v h2; h2[0] = (_Float16)gx; h2[1] = (_Float16)gy;
                *(half2v*)&G[ni * K1P + 64] = h2;
                G[ni * K1P + 66] = (_Float16)gz;
            }
        }
        __syncthreads();

        if (tid < 256) {
            // ---- layer 1: K=96 (3 steps), out 64 ch ----
            {
                floatx4 acc[4] = {};
#pragma unroll
                for (int ks = 0; ks < 3; ++ks) {
                    half8v bf = *(const half8v*)&G[myrow * K1P + ks * 32 + qd * 8];
#pragma unroll
                    for (int mt = 0; mt < 4; ++mt)
                        acc[mt] = __builtin_amdgcn_mfma_f32_16x16x32_f16(a1[ks][mt], bf, acc[mt], 0, 0, 0);
                }
#pragma unroll
                for (int mt = 0; mt < 4; ++mt) {
                    float4 bb = *(const float4*)&Lb[mt * 16 + qd * 4];
                    half4v h;
                    h[0] = (_Float16)fmaxf(acc[mt][0] + bb.x, 0.f);
                    h[1] = (_Float16)fmaxf(acc[mt][1] + bb.y, 0.f);
                    h[2] = (_Float16)fmaxf(acc[mt][2] + bb.z, 0.f);
                    h[3] = (_Float16)fmaxf(acc[mt][3] + bb.w, 0.f);
                    *(half4v*)&H1[myrow * K2P + mt * 16 + qd * 4] = h;
                }
            }
            // ---- layer 2: K=64 (2 steps), out 64 ch ----
            {
                floatx4 acc[4] = {};
#pragma unroll
                for (int ks = 0; ks < 2; ++ks) {
                    half8v bf = *(const half8v*)&H1[myrow * K2P + ks * 32 + qd * 8];
#pragma unroll
                    for (int mt = 0; mt < 4; ++mt)
                        acc[mt] = __builtin_amdgcn_mfma_f32_16x16x32_f16(a2[ks][mt], bf, acc[mt], 0, 0, 0);
                }
#pragma unroll
                for (int mt = 0; mt < 4; ++mt) {
                    float4 bb = *(const float4*)&Lb[64 + mt * 16 + qd * 4];
                    half4v h;
                    h[0] = (_Float16)fmaxf(acc[mt][0] + bb.x, 0.f);
                    h[1] = (_Float16)fmaxf(acc[mt][1] + bb.y, 0.f);
                    h[2] = (_Float16)fmaxf(acc[mt][2] + bb.z, 0.f);
                    h[3] = (_Float16)fmaxf(acc[mt][3] + bb.w, 0.f);
                    *(half4v*)&H2[myrow * K2P + mt * 16 + qd * 4] = h;
                }
            }
            // ---- layer 3 (swapped operands): C rows = neighbors ----
            {
                floatx4 acc3[8] = {};
#pragma unroll
                for (int ks = 0; ks < 2; ++ks) {
                    half8v av = *(const half8v*)&H2[myrow * K2P + ks * 32 + qd * 8];
#pragma unroll
                    for (int mt = 0; mt < 8; ++mt)
                        acc3[mt] = __builtin_amdgcn_mfma_f32_16x16x32_f16(av, a3[ks][mt], acc3[mt], 0, 0, 0);
                }
                const short* np4 = &nbr_s[wv * 16 + qd * 4];
                const bool v0 = np4[0] >= 0, v1 = np4[1] >= 0;
                const bool v2 = np4[2] >= 0, v3 = np4[3] >= 0;
#pragma unroll
                for (int mt = 0; mt < 8; ++mt) {
                    float m = v0 ? acc3[mt][0] : -INFINITY;
                    m = fmaxf(m, v1 ? acc3[mt][1] : -INFINITY);
                    m = fmaxf(m, v2 ? acc3[mt][2] : -INFINITY);
                    m = fmaxf(m, v3 ? acc3[mt][3] : -INFINITY);
                    m = fmaxf(m, __shfl_xor(m, 16));
                    m = fmaxf(m, __shfl_xor(m, 32));
                    if (qd == 0) CW[wv * NCO + mt * 16 + c] = m;
                }
            }
        }
        __syncthreads();

        if (tid < NCO) {
            float m = fmaxf(fmaxf(CW[tid], CW[NCO + tid]),
                            fmaxf(CW[2 * NCO + tid], CW[3 * NCO + tid]));
            m += b3r;                                  // exact: add after max
            if (nbr_s[NK - 1] < 0) m = fmaxf(m, 0.f);  // ref's masked zeros
            out[(size_t)bs * NCO + tid] = m;
        }
        __syncthreads();   // protect nbr_s/G/CW before next query's ballq/gather
    }
}

extern "C" void kernel_launch(void* const* d_in, const int* in_sizes, int n_in,
                              void* d_out, int out_size, void* d_ws, size_t ws_size,
                              hipStream_t stream) {
    const float* x   = (const float*)d_in[0];
    const float* pos = (const float*)d_in[1];
    const float* W1  = (const float*)d_in[2];
    const float* b1  = (const float*)d_in[3];
    const float* W2  = (const float*)d_in[4];
    const float* b2  = (const float*)d_in[5];
    const float* W3  = (const float*)d_in[6];
    const float* b3  = (const float*)d_in[7];

    float* out0 = (float*)d_out;                        // [B,S,128]
    float* nxyz = out0 + (size_t)NB * NS * NCO;         // [B,S,3]
    int*      widxp = (int*)((char*)d_ws + WS_WIDX);    // tokens (0xAA poison < 0)
    _Float16* wtp   = (_Float16*)((char*)d_ws + WS_WT); // f16 weights, 40 KB

    wt_kernel<<<256, 64, 0, stream>>>(W1, W2, W3, wtp);
    fused_kernel<<<256, 512, 0, stream>>>(x, pos, b1, b2, b3, wtp,
                                          nxyz, out0, widxp);
}